// Round 14
// baseline (67.746 us; speedup 1.0000x reference)
//
#include <hip/hip_runtime.h>
#include <math.h>

#define B_ 4096
#define T_ 64
#define E_ 256
#define H_ 64
#define V_ 32000
#define THREADS 512

typedef __attribute__((ext_vector_type(8))) short bf16x8;
typedef __attribute__((ext_vector_type(4))) float f32x4;
typedef __attribute__((ext_vector_type(4))) unsigned int u32x4;

__device__ __forceinline__ short f2bf(float x) {
    unsigned u = __float_as_uint(x);
    return (short)((u + 0x7FFFu + ((u >> 16) & 1u)) >> 16);
}
__device__ __forceinline__ unsigned cvt_pk_bf16(float lo, float hi) {
    unsigned r;
    asm("v_cvt_pk_bf16_f32 %0, %1, %2" : "=v"(r) : "v"(lo), "v"(hi));
    return r;
}
__device__ __forceinline__ float exp2_raw(float x) {
    float r; asm("v_exp_f32 %0, %1" : "=v"(r) : "v"(x)); return r;
}
__device__ __forceinline__ float rcp_raw(float x) {
    float r; asm("v_rcp_f32 %0, %1" : "=v"(r) : "v"(x)); return r;
}
#define LOG2E 1.442695041f

// quad_perm DPP lane exchange (VALU, not DS): xor1 = 0xB1, xor2 = 0x4E.
template <int CTRL>
__device__ __forceinline__ float dpp_f(float x) {
    return __int_as_float(
        __builtin_amdgcn_mov_dpp(__float_as_int(x), CTRL, 0xF, 0xF, true));
}

__device__ __forceinline__ void gld16(const void* g, void* l) {
    __builtin_amdgcn_global_load_lds(
        (const __attribute__((address_space(1))) void*)g,
        (__attribute__((address_space(3))) void*)l, 16, 0, 0);
}

// ---------------------------------------------------------------------------
// Prep (wih_frag layout identical to R4-R13, verified):
//  wih_frag[((vv*2+tl)*8 + kc)*512 + lane*8 + jj]:
//    gate g = tl*128 + (lane&1)*64 + vv*8 + ((lane&15)>>1)
//    k      = kc*32 + (lane>>4)*8 + jj
//  whh_g: bf16 [g][k] row-major;  bias_f = b_ih + b_hh
//  emb_bf: whole table bf16 (RNE) for global_load_lds staging.
// ---------------------------------------------------------------------------
__global__ void prep_kernel(const float* __restrict__ W_ih,
                            const float* __restrict__ W_hh,
                            const float* __restrict__ b_ih,
                            const float* __restrict__ b_hh,
                            const float* __restrict__ emb_table,
                            short* __restrict__ wih_frag,
                            short* __restrict__ whh_g,
                            float* __restrict__ bias_f,
                            short* __restrict__ emb_bf,
                            int tabN) {
    int tid = blockIdx.x * blockDim.x + threadIdx.x;
    int stride = gridDim.x * blockDim.x;
    for (int i = tid; i < 65536; i += stride) {
        int jj = i & 7;
        int l  = (i >> 3) & 63;
        int kc = (i >> 9) & 7;
        int tl = (i >> 12) & 1;
        int vv = i >> 13;
        int uu = (l & 15) >> 1, pp = l & 1;
        int g = tl * 128 + pp * 64 + vv * 8 + uu;
        int k = kc * 32 + (l >> 4) * 8 + jj;
        wih_frag[i] = f2bf(W_ih[g * E_ + k]);
    }
    for (int i = tid; i < 256 * 64; i += stride) whh_g[i] = f2bf(W_hh[i]);
    for (int i = tid; i < 256; i += stride) bias_f[i] = b_ih[i] + b_hh[i];
    for (int i = tid; i < (tabN >> 2); i += stride) {
        float4 v = ((const float4*)emb_table)[i];
        uint2 w;
        w.x = cvt_pk_bf16(v.x, v.y);
        w.y = cvt_pk_bf16(v.z, v.w);
        ((uint2*)emb_bf)[i] = w;
    }
}

// ---------------------------------------------------------------------------
// All-compute-wave MFMA LSTM. grid 256 (1 block/CU), 512 threads = 8 waves,
// pinned waves_per_eu(2,2) -> 256-VGPR budget (unlocks split-K + reg-held G).
// Wave w owns vv=w (32 gate cols) AND stages chunk kc=w of emb(t+3) via one
// async global_load_lds dwordx4 per step (bf16 table; clamped tail re-stage
// keeps 1 issue/step so vmcnt(1) at each barrier retires the 2-step-old load
// before its buffer is read).
// Per step: [stage DMA issue] -> R: h(t-1)*Whh on 4 INDEPENDENT acc chains
// (split-K: a0/a1 for i|f, b0/b1 for g|o; depth 5 not 10) -> merge to ga/gb
// (regs; no LDS stash) ->
//   waves 0-3: gates -> h-write -> P(t+1)
//   waves 4-7: P(t+1) -> gates -> h-write     (anti-phase: each SIMD's two
//   waves are in opposite phases -> MFMA and trans pipes interleave)
// Gates: raw v_exp/v_rcp + quad_perm DPP exchanges (VALU-only).
// Fragment LDS layout (zero-conflict): chunk (kc,lane) at kc*1024B + lane*16B
//   holds A[m=lane&15][k=kc*32+(lane>>4)*8+jj].
// ---------------------------------------------------------------------------
template <int TAB>
__global__ __attribute__((amdgpu_flat_work_group_size(THREADS, THREADS),
                          amdgpu_waves_per_eu(2, 2)))
void lstm_f(const int* __restrict__ x,
            const float* __restrict__ embf,
            const short* __restrict__ embb,
            const short* __restrict__ wih_frag,
            const short* __restrict__ whh_g,
            const float* __restrict__ bias_f,
            float* __restrict__ out) {
    __shared__ __align__(16) short s_ef[4][4096];   // 4-ring emb, 8 KB each
    __shared__ __align__(16) short s_hf[2][1024];   // 2-ring h, 2 KB each
    __shared__ int s_idx[1024];                     // [t][m]

    const int tid  = threadIdx.x;
    const int lane = tid & 63;
    const int wave = tid >> 6;
    const int r0   = blockIdx.x * 16;

    {
        const int tt = tid & 63;
        const int mA = tid >> 6;
        s_idx[tt * 16 + mA]     = x[(r0 + mA) * T_ + tt];
        s_idx[tt * 16 + mA + 8] = x[(r0 + mA + 8) * T_ + tt];
    }
    ((int*)s_hf)[tid]       = 0;
    ((int*)s_hf)[tid + 512] = 0;

    const int p  = lane & 1;
    const int c4 = lane >> 4;
    const int u  = (lane & 15) >> 1;
    const float scl2 = p ? 1.0f : 2.0f;
    const float offB = p ? 0.0f : -1.0f;
    const float enB  = -LOG2E * scl2;
    const int m0 = c4 * 4 + p * 2;

    // ---- weights (register-resident) ----
    bf16x8 wA[8], wB[8], qA0, qA1, qB0, qB1;
    float bA, bB;
    int hw_s;
    {
        const short* wp = wih_frag + wave * 8192 + lane * 8;
        #pragma unroll
        for (int kc = 0; kc < 8; ++kc) {
            wA[kc] = *(const bf16x8*)(wp + kc * 512);
            wB[kc] = *(const bf16x8*)(wp + 4096 + kc * 512);
        }
        const int gA = p * 64 + wave * 8 + u;
        const short* qp = whh_g + gA * 64 + c4 * 8;
        qA0 = *(const bf16x8*)(qp);
        qA1 = *(const bf16x8*)(qp + 32);
        qB0 = *(const bf16x8*)(qp + 8192);
        qB1 = *(const bf16x8*)(qp + 8192 + 32);
        bA = bias_f[gA];
        bB = bias_f[gA + 128];
        hw_s = (wave >> 2) * 512 + (wave & 3) * 128
             + ((u & 1) ? (m0 + 1) * 8 + (u - 1) : m0 * 8 + u);
    }

    // ---- self-stage mapping: wave owns chunk kc=wave ----
    const int m16   = lane & 15;
    const int sbase = wave * 512 + lane * 8;                 // shorts (TAB=0)
    const int skoff = wave * 32 + (lane >> 4) * 8;           // emb col

    __syncthreads();   // s_idx, h=0 visible

    // ---- prologue: stage t=0,1,2 (0,1 must land; 2 may stay in flight) ----
    #pragma unroll
    for (int tt = 0; tt < 3; ++tt) {
        int tok = s_idx[tt * 16 + m16];
        if (TAB) {
            gld16(embb + (size_t)tok * E_ + skoff, &s_ef[tt][wave * 512]);
        } else {
            const float* pr = embf + (size_t)tok * E_ + skoff;
            float4 f0 = *(const float4*)pr;
            float4 f1 = *(const float4*)(pr + 4);
            u32x4 w;
            w[0] = cvt_pk_bf16(f0.x, f0.y);
            w[1] = cvt_pk_bf16(f0.z, f0.w);
            w[2] = cvt_pk_bf16(f1.x, f1.y);
            w[3] = cvt_pk_bf16(f1.z, f1.w);
            *(u32x4*)(&s_ef[tt][0] + sbase) = w;
        }
    }
    if (TAB) {
        asm volatile("s_waitcnt vmcnt(1) lgkmcnt(0)" ::: "memory");
        __builtin_amdgcn_s_barrier();
        __builtin_amdgcn_sched_barrier(0);
    } else {
        __syncthreads();
    }

    float c0 = 0.f, c1 = 0.f, h0v = 0.f, h1v = 0.f;
    f32x4 a0, a1, b0, b1;   // split-K accumulator chains

    // ---- compute prologue: pre-gates P(0) from buf0 (split-K) ----
    {
        a0 = (f32x4){bA, bA, bA, bA};
        b0 = (f32x4){bB, bB, bB, bB};
        a1 = (f32x4){0.f, 0.f, 0.f, 0.f};
        b1 = (f32x4){0.f, 0.f, 0.f, 0.f};
        const short* eb = &s_ef[0][0] + lane * 8;
        #pragma unroll
        for (int kc = 0; kc < 4; ++kc) {
            bf16x8 av = *(const bf16x8*)(eb + kc * 512);
            bf16x8 aw = *(const bf16x8*)(eb + (kc + 4) * 512);
            a0 = __builtin_amdgcn_mfma_f32_16x16x32_bf16(av, wA[kc], a0, 0, 0, 0);
            b0 = __builtin_amdgcn_mfma_f32_16x16x32_bf16(av, wB[kc], b0, 0, 0, 0);
            a1 = __builtin_amdgcn_mfma_f32_16x16x32_bf16(aw, wA[kc + 4], a1, 0, 0, 0);
            b1 = __builtin_amdgcn_mfma_f32_16x16x32_bf16(aw, wB[kc + 4], b1, 0, 0, 0);
        }
    }

    // gates: full gate math from merged pre-activations, h-write for step t
    auto gates_phase = [&](const float* ga, const float* gb, int t) {
        float sA[4], Bv[4];
        #pragma unroll
        for (int q = 0; q < 4; ++q) {
            sA[q] = rcp_raw(1.0f + exp2_raw(-LOG2E * ga[q]));           // sigm(i)|sigm(f)
            Bv[q] = rcp_raw(1.0f + exp2_raw(enB * gb[q])) * scl2 + offB; // tanh(g)|sigm(o)
        }
        float s1 = p ? sA[0] : sA[2] * Bv[2];
        float r1 = dpp_f<0xB1>(s1);
        float s2 = p ? sA[1] : sA[3] * Bv[3];
        float r2 = dpp_f<0xB1>(s2);
        float r3 = dpp_f<0xB1>(Bv[0]);
        float r4 = dpp_f<0xB1>(Bv[1]);
        float fc0 = p ? sA[2] : r1;
        float ic0 = p ? r1 : sA[0] * Bv[0];
        float oc0 = p ? Bv[2] : r3;
        float fc1 = p ? sA[3] : r2;
        float ic1 = p ? r2 : sA[1] * Bv[1];
        float oc1 = p ? Bv[3] : r4;
        c0 = fc0 * c0 + ic0;
        c1 = fc1 * c1 + ic1;
        h0v = oc0 * (1.0f - 2.0f * rcp_raw(1.0f + exp2_raw(2.0f * LOG2E * c0)));
        h1v = oc1 * (1.0f - 2.0f * rcp_raw(1.0f + exp2_raw(2.0f * LOG2E * c1)));
        float snd = (u & 1) ? h0v : h1v;
        float rcv = dpp_f<0x4E>(snd);
        unsigned hw = (u & 1) ? cvt_pk_bf16(rcv, h1v) : cvt_pk_bf16(h0v, rcv);
        *(unsigned*)(&s_hf[(t + 1) & 1][0] + hw_s) = hw;
    };

    auto p_phase = [&](int t) {   // preG(t+1), split-K chains
        a0 = (f32x4){bA, bA, bA, bA};
        b0 = (f32x4){bB, bB, bB, bB};
        a1 = (f32x4){0.f, 0.f, 0.f, 0.f};
        b1 = (f32x4){0.f, 0.f, 0.f, 0.f};
        const short* eb = &s_ef[(t + 1) & 3][0] + lane * 8;
        __builtin_amdgcn_s_setprio(1);
        #pragma unroll
        for (int kc = 0; kc < 4; ++kc) {
            bf16x8 av = *(const bf16x8*)(eb + kc * 512);
            bf16x8 aw = *(const bf16x8*)(eb + (kc + 4) * 512);
            a0 = __builtin_amdgcn_mfma_f32_16x16x32_bf16(av, wA[kc], a0, 0, 0, 0);
            b0 = __builtin_amdgcn_mfma_f32_16x16x32_bf16(av, wB[kc], b0, 0, 0, 0);
            a1 = __builtin_amdgcn_mfma_f32_16x16x32_bf16(aw, wA[kc + 4], a1, 0, 0, 0);
            b1 = __builtin_amdgcn_mfma_f32_16x16x32_bf16(aw, wB[kc + 4], b1, 0, 0, 0);
        }
        __builtin_amdgcn_s_setprio(0);
    };

    #pragma unroll 4
    for (int t = 0; t < T_; ++t) {
        // ---- issue stage DMA for emb(t+3) (clamped: exactly 1 issue/step) ----
        {
            const int ts = (t + 3 < T_) ? t + 3 : T_ - 1;
            int tok = s_idx[ts * 16 + m16];
            if (TAB) {
                gld16(embb + (size_t)tok * E_ + skoff,
                      &s_ef[(t + 3) & 3][wave * 512]);
            } else {
                const float* pr = embf + (size_t)tok * E_ + skoff;
                float4 f0 = *(const float4*)pr;
                float4 f1 = *(const float4*)(pr + 4);
                u32x4 w;
                w[0] = cvt_pk_bf16(f0.x, f0.y);
                w[1] = cvt_pk_bf16(f0.z, f0.w);
                w[2] = cvt_pk_bf16(f1.x, f1.y);
                w[3] = cvt_pk_bf16(f1.z, f1.w);
                *(u32x4*)(&s_ef[(t + 3) & 3][0] + sbase) = w;
            }
        }

        // ---- R: G(t) = preG + h(t-1)*Whh (4 independent chains) ----
        const short* hb = &s_hf[t & 1][0] + lane * 8;
        bf16x8 hv0 = *(const bf16x8*)(hb);
        bf16x8 hv1 = *(const bf16x8*)(hb + 512);
        __builtin_amdgcn_s_setprio(1);
        a0 = __builtin_amdgcn_mfma_f32_16x16x32_bf16(hv0, qA0, a0, 0, 0, 0);
        a1 = __builtin_amdgcn_mfma_f32_16x16x32_bf16(hv1, qA1, a1, 0, 0, 0);
        b0 = __builtin_amdgcn_mfma_f32_16x16x32_bf16(hv0, qB0, b0, 0, 0, 0);
        b1 = __builtin_amdgcn_mfma_f32_16x16x32_bf16(hv1, qB1, b1, 0, 0, 0);
        __builtin_amdgcn_s_setprio(0);

        // ---- merge split-K into registers (no LDS stash) ----
        float ga[4], gb[4];
        #pragma unroll
        for (int q = 0; q < 4; ++q) {
            ga[q] = a0[q] + a1[q];
            gb[q] = b0[q] + b1[q];
        }

        if (wave < 4) {
            // ---- group A: gates first, then P ----
            gates_phase(ga, gb, t);
            if (t < T_ - 1) p_phase(t);
        } else {
            // ---- group B: P first, then gates (anti-phase) ----
            __builtin_amdgcn_sched_barrier(0);
            if (t < T_ - 1) p_phase(t);
            __builtin_amdgcn_sched_barrier(0);
            gates_phase(ga, gb, t);
        }

        if (TAB) {
            // fresh DMA stays in flight; the 2-step-old one must retire
            asm volatile("s_waitcnt vmcnt(1) lgkmcnt(0)" ::: "memory");
            __builtin_amdgcn_s_barrier();
            __builtin_amdgcn_sched_barrier(0);
        } else {
            __syncthreads();
        }
    }

    {
        const int j = wave * 8 + u;
        out[(r0 + m0) * H_ + j]     = h0v;
        out[(r0 + m0 + 1) * H_ + j] = h1v;
    }
}

// ---------------------------------------------------------------------------
extern "C" void kernel_launch(void* const* d_in, const int* in_sizes, int n_in,
                              void* d_out, int out_size, void* d_ws, size_t ws_size,
                              hipStream_t stream) {
    const int*   x         = (const int*)d_in[0];
    const float* emb_table = (const float*)d_in[1];
    const float* W_ih      = (const float*)d_in[2];
    const float* W_hh      = (const float*)d_in[3];
    const float* b_ih      = (const float*)d_in[4];
    const float* b_hh      = (const float*)d_in[5];
    float*       out       = (float*)d_out;

    short* wih_frag = (short*)d_ws;               // 65536 shorts (128 KB)
    short* whh_g    = wih_frag + 65536;           // 16384 shorts (32 KB)
    float* bias_f   = (float*)(whh_g + 16384);    // 256 floats (1 KB)
    short* emb_bf   = (short*)(bias_f + 256);     // 8.192M shorts (16.4 MB)

    const size_t need = (size_t)(65536 + 16384) * 2 + 256 * 4
                      + (size_t)V_ * E_ * 2;
    const int tab = (ws_size >= need) ? 1 : 0;

    prep_kernel<<<tab ? 1024 : 64, 256, 0, stream>>>(
        W_ih, W_hh, b_ih, b_hh, emb_table,
        wih_frag, whh_g, bias_f,
        tab ? emb_bf : wih_frag, tab ? V_ * E_ : 0);

    if (tab) {
        lstm_f<1><<<B_ / 16, THREADS, 0, stream>>>(
            x, emb_table, emb_bf, wih_frag, whh_g, bias_f, out);
    } else {
        lstm_f<0><<<B_ / 16, THREADS, 0, stream>>>(
            x, emb_table, wih_frag, wih_frag, whh_g, bias_f, out);
    }
}

// Round 15
// 66.329 us; speedup vs baseline: 1.0214x; 1.0214x over previous
//
#include <hip/hip_runtime.h>
#include <math.h>

#define B_ 4096
#define T_ 64
#define E_ 256
#define H_ 64
#define V_ 32000
#define THREADS 1024

typedef __attribute__((ext_vector_type(8))) short bf16x8;
typedef __attribute__((ext_vector_type(4))) float f32x4;
typedef __attribute__((ext_vector_type(4))) unsigned int u32x4;

__device__ __forceinline__ short f2bf(float x) {
    unsigned u = __float_as_uint(x);
    return (short)((u + 0x7FFFu + ((u >> 16) & 1u)) >> 16);
}
__device__ __forceinline__ unsigned cvt_pk_bf16(float lo, float hi) {
    unsigned r;
    asm("v_cvt_pk_bf16_f32 %0, %1, %2" : "=v"(r) : "v"(lo), "v"(hi));
    return r;
}
__device__ __forceinline__ float exp2_raw(float x) {
    float r; asm("v_exp_f32 %0, %1" : "=v"(r) : "v"(x)); return r;
}
__device__ __forceinline__ float rcp_raw(float x) {
    float r; asm("v_rcp_f32 %0, %1" : "=v"(r) : "v"(x)); return r;
}
#define LOG2E 1.442695041f

// quad_perm DPP lane exchange (VALU, not DS): xor1 = 0xB1, xor2 = 0x4E.
template <int CTRL>
__device__ __forceinline__ float dpp_f(float x) {
    return __int_as_float(
        __builtin_amdgcn_mov_dpp(__float_as_int(x), CTRL, 0xF, 0xF, true));
}

__device__ __forceinline__ void gld16(const void* g, void* l) {
    __builtin_amdgcn_global_load_lds(
        (const __attribute__((address_space(1))) void*)g,
        (__attribute__((address_space(3))) void*)l, 16, 0, 0);
}

// ---------------------------------------------------------------------------
// Prep (wih_frag layout identical to R4-R14, verified):
//  wih_frag[((vv*2+tl)*8 + kc)*512 + lane*8 + jj]:
//    gate g = tl*128 + (lane&1)*64 + vv*8 + ((lane&15)>>1)
//    k      = kc*32 + (lane>>4)*8 + jj
//  whh_g: bf16 [g][k] row-major;  bias_f = b_ih + b_hh
//  emb_bf: whole table bf16 (RNE); uint4-wide conversion (8 floats/iter).
// ---------------------------------------------------------------------------
__global__ void prep_kernel(const float* __restrict__ W_ih,
                            const float* __restrict__ W_hh,
                            const float* __restrict__ b_ih,
                            const float* __restrict__ b_hh,
                            const float* __restrict__ emb_table,
                            short* __restrict__ wih_frag,
                            short* __restrict__ whh_g,
                            float* __restrict__ bias_f,
                            short* __restrict__ emb_bf,
                            int tabN) {
    int tid = blockIdx.x * blockDim.x + threadIdx.x;
    int stride = gridDim.x * blockDim.x;
    for (int i = tid; i < 65536; i += stride) {
        int jj = i & 7;
        int l  = (i >> 3) & 63;
        int kc = (i >> 9) & 7;
        int tl = (i >> 12) & 1;
        int vv = i >> 13;
        int uu = (l & 15) >> 1, pp = l & 1;
        int g = tl * 128 + pp * 64 + vv * 8 + uu;
        int k = kc * 32 + (l >> 4) * 8 + jj;
        wih_frag[i] = f2bf(W_ih[g * E_ + k]);
    }
    for (int i = tid; i < 256 * 64; i += stride) whh_g[i] = f2bf(W_hh[i]);
    for (int i = tid; i < 256; i += stride) bias_f[i] = b_ih[i] + b_hh[i];
    // 8 floats -> 4x cvt_pk -> one 16B store per iteration
    for (int i = tid; i < (tabN >> 3); i += stride) {
        float4 v0 = ((const float4*)emb_table)[i * 2];
        float4 v1 = ((const float4*)emb_table)[i * 2 + 1];
        u32x4 w;
        w[0] = cvt_pk_bf16(v0.x, v0.y);
        w[1] = cvt_pk_bf16(v0.z, v0.w);
        w[2] = cvt_pk_bf16(v1.x, v1.y);
        w[3] = cvt_pk_bf16(v1.z, v1.w);
        ((u32x4*)emb_bf)[i] = w;
    }
}

// ---------------------------------------------------------------------------
// R13 structure (best measured: 61.4us kernel) with the stash conflict fixed.
// grid 256 (1 block/CU), 1024 threads = 16 waves, pinned 4 waves/EU.
//  waves 0-3 (group A): R -> gates -> h-write -> P(t+1)
//  waves 4-7 (group B): R -> stash G -> P(t+1) -> unstash -> gates
//       (anti-phase: each SIMD's two compute waves are in opposite phases)
//  waves 8-15 (stage): wave 8+s stages chunk kc=s of emb(t+3) via ONE
//       global_load_lds dwordx4 (bf16 table), distance-3 prefetch, 4-ring,
//       counted-vmcnt barrier (vmcnt(1)).
// STASH FIX (R13 post-mortem): GA and GB now live in separate 4KB regions at
// 16B/lane stride -> consecutive lanes hit consecutive banks, conflict-free
// (R13 interleaved them at 32B/lane: bank period 4 -> ~16-way, 1.7M cycles).
// Gates: raw v_exp/v_rcp + quad_perm DPP exchanges (VALU-only).
// Fragment LDS layout (zero-conflict): chunk (kc,lane) at kc*1024B + lane*16B.
// ---------------------------------------------------------------------------
template <int TAB>
__global__ __attribute__((amdgpu_flat_work_group_size(THREADS, THREADS),
                          amdgpu_waves_per_eu(4, 4)))
void lstm_f(const int* __restrict__ x,
            const float* __restrict__ embf,
            const short* __restrict__ embb,
            const short* __restrict__ wih_frag,
            const short* __restrict__ whh_g,
            const float* __restrict__ bias_f,
            float* __restrict__ out) {
    __shared__ __align__(16) short s_ef[4][4096];   // 4-ring emb, 8 KB each
    __shared__ __align__(16) short s_hf[2][1024];   // 2-ring h, 2 KB each
    __shared__ __align__(16) float s_gst[2048];     // stash: GA [0,1024), GB [1024,2048)
    __shared__ int s_idx[1024];                     // [t][m]

    const int tid  = threadIdx.x;
    const int lane = tid & 63;
    const int wave = tid >> 6;
    const int r0   = blockIdx.x * 16;

    s_idx[(tid & 63) * 16 + (tid >> 6)] = x[(r0 + (tid >> 6)) * T_ + (tid & 63)];
    ((int*)s_hf)[tid] = 0;

    const int p  = lane & 1;
    const int c4 = lane >> 4;
    const int u  = (lane & 15) >> 1;
    const float scl2 = p ? 1.0f : 2.0f;
    const float offB = p ? 0.0f : -1.0f;
    const float enB  = -LOG2E * scl2;
    const int m0 = c4 * 4 + p * 2;

    // ---- compute-wave setup ----
    bf16x8 wA[8], wB[8], qA0, qA1, qB0, qB1;
    float bA = 0.f, bB = 0.f;
    int hw_s = 0;
    if (wave < 8) {
        const short* wp = wih_frag + wave * 8192 + lane * 8;
        #pragma unroll
        for (int kc = 0; kc < 8; ++kc) {
            wA[kc] = *(const bf16x8*)(wp + kc * 512);
            wB[kc] = *(const bf16x8*)(wp + 4096 + kc * 512);
        }
        const int gA = p * 64 + wave * 8 + u;
        const short* qp = whh_g + gA * 64 + c4 * 8;
        qA0 = *(const bf16x8*)(qp);
        qA1 = *(const bf16x8*)(qp + 32);
        qB0 = *(const bf16x8*)(qp + 8192);
        qB1 = *(const bf16x8*)(qp + 8192 + 32);
        bA = bias_f[gA];
        bB = bias_f[gA + 128];
        hw_s = (wave >> 2) * 512 + (wave & 3) * 128
             + ((u & 1) ? (m0 + 1) * 8 + (u - 1) : m0 * 8 + u);
    }

    // ---- stage-wave mapping: wave 8+s owns chunk kc=s ----
    const int m16   = lane & 15;
    const int sbase = (wave - 8) * 512 + lane * 8;                 // shorts
    const int skoff = (wave - 8) * 32 + (lane >> 4) * 8;           // emb col

    __syncthreads();   // s_idx, h=0 visible

    if (wave >= 8) {
        // prologue: stage t=0,1,2 (0,1 must land; 2 may stay in flight)
        #pragma unroll
        for (int tt = 0; tt < 3; ++tt) {
            int tok = s_idx[tt * 16 + m16];
            if (TAB) {
                gld16(embb + (size_t)tok * E_ + skoff,
                      &s_ef[tt][(wave - 8) * 512]);
            } else {
                const float* pr = embf + (size_t)tok * E_ + skoff;
                float4 f0 = *(const float4*)pr;
                float4 f1 = *(const float4*)(pr + 4);
                u32x4 w;
                w[0] = cvt_pk_bf16(f0.x, f0.y);
                w[1] = cvt_pk_bf16(f0.z, f0.w);
                w[2] = cvt_pk_bf16(f1.x, f1.y);
                w[3] = cvt_pk_bf16(f1.z, f1.w);
                *(u32x4*)(&s_ef[tt][0] + sbase) = w;
            }
        }
    }
    if (TAB) {
        asm volatile("s_waitcnt vmcnt(1) lgkmcnt(0)" ::: "memory");
        __builtin_amdgcn_s_barrier();
        __builtin_amdgcn_sched_barrier(0);
    } else {
        __syncthreads();
    }

    float c0 = 0.f, c1 = 0.f, h0v = 0.f, h1v = 0.f;
    f32x4 pA, pB;
    // conflict-free stash slots: 16B/lane stride within each 4KB region
    float* sgA = s_gst + (wave & 3) * 256 + lane * 4;
    float* sgB = s_gst + 1024 + (wave & 3) * 256 + lane * 4;

    // ---- compute prologue: pre-gates P(0) from buf0 ----
    if (wave < 8) {
        pA = (f32x4){bA, bA, bA, bA};
        pB = (f32x4){bB, bB, bB, bB};
        const short* eb = &s_ef[0][0] + lane * 8;
        #pragma unroll
        for (int kc = 0; kc < 8; ++kc) {
            bf16x8 av = *(const bf16x8*)(eb + kc * 512);
            pA = __builtin_amdgcn_mfma_f32_16x16x32_bf16(av, wA[kc], pA, 0, 0, 0);
            pB = __builtin_amdgcn_mfma_f32_16x16x32_bf16(av, wB[kc], pB, 0, 0, 0);
        }
    }

    // gates: full gate math from pre-activations GA/GB, h-write for step t
    auto gates_phase = [&](f32x4 GA, f32x4 GB, int t) {
        float sA[4], Bv[4];
        #pragma unroll
        for (int q = 0; q < 4; ++q) {
            sA[q] = rcp_raw(1.0f + exp2_raw(-LOG2E * GA[q]));          // sigm(i)|sigm(f)
            Bv[q] = rcp_raw(1.0f + exp2_raw(enB * GB[q])) * scl2 + offB; // tanh(g)|sigm(o)
        }
        float s1 = p ? sA[0] : sA[2] * Bv[2];
        float r1 = dpp_f<0xB1>(s1);
        float s2 = p ? sA[1] : sA[3] * Bv[3];
        float r2 = dpp_f<0xB1>(s2);
        float r3 = dpp_f<0xB1>(Bv[0]);
        float r4 = dpp_f<0xB1>(Bv[1]);
        float fc0 = p ? sA[2] : r1;
        float ic0 = p ? r1 : sA[0] * Bv[0];
        float oc0 = p ? Bv[2] : r3;
        float fc1 = p ? sA[3] : r2;
        float ic1 = p ? r2 : sA[1] * Bv[1];
        float oc1 = p ? Bv[3] : r4;
        c0 = fc0 * c0 + ic0;
        c1 = fc1 * c1 + ic1;
        h0v = oc0 * (1.0f - 2.0f * rcp_raw(1.0f + exp2_raw(2.0f * LOG2E * c0)));
        h1v = oc1 * (1.0f - 2.0f * rcp_raw(1.0f + exp2_raw(2.0f * LOG2E * c1)));
        float snd = (u & 1) ? h0v : h1v;
        float rcv = dpp_f<0x4E>(snd);
        unsigned hw = (u & 1) ? cvt_pk_bf16(rcv, h1v) : cvt_pk_bf16(h0v, rcv);
        *(unsigned*)(&s_hf[(t + 1) & 1][0] + hw_s) = hw;
    };

    auto p_phase = [&](int t) {   // preG(t+1) into pA/pB
        pA = (f32x4){bA, bA, bA, bA};
        pB = (f32x4){bB, bB, bB, bB};
        const short* eb = &s_ef[(t + 1) & 3][0] + lane * 8;
        __builtin_amdgcn_s_setprio(1);
        #pragma unroll
        for (int kc = 0; kc < 8; ++kc) {
            bf16x8 av = *(const bf16x8*)(eb + kc * 512);
            pA = __builtin_amdgcn_mfma_f32_16x16x32_bf16(av, wA[kc], pA, 0, 0, 0);
            pB = __builtin_amdgcn_mfma_f32_16x16x32_bf16(av, wB[kc], pB, 0, 0, 0);
        }
        __builtin_amdgcn_s_setprio(0);
    };

    #pragma unroll 4
    for (int t = 0; t < T_; ++t) {
        if (wave < 8) {
            // ---- R: G(t) = preG + h(t-1)*Whh ----
            const short* hb = &s_hf[t & 1][0] + lane * 8;
            bf16x8 hv0 = *(const bf16x8*)(hb);
            bf16x8 hv1 = *(const bf16x8*)(hb + 512);
            __builtin_amdgcn_s_setprio(1);
            pA = __builtin_amdgcn_mfma_f32_16x16x32_bf16(hv0, qA0, pA, 0, 0, 0);
            pA = __builtin_amdgcn_mfma_f32_16x16x32_bf16(hv1, qA1, pA, 0, 0, 0);
            pB = __builtin_amdgcn_mfma_f32_16x16x32_bf16(hv0, qB0, pB, 0, 0, 0);
            pB = __builtin_amdgcn_mfma_f32_16x16x32_bf16(hv1, qB1, pB, 0, 0, 0);
            __builtin_amdgcn_s_setprio(0);

            if (wave < 4) {
                // ---- group A: gates first, then P ----
                gates_phase(pA, pB, t);
                if (t < T_ - 1) p_phase(t);
            } else {
                // ---- group B: stash G (conflict-free), P first, then gates ----
                *(f32x4*)sgA = pA;
                *(f32x4*)sgB = pB;
                __builtin_amdgcn_sched_barrier(0);
                if (t < T_ - 1) p_phase(t);
                __builtin_amdgcn_sched_barrier(0);
                f32x4 GA = *(const f32x4*)sgA;
                f32x4 GB = *(const f32x4*)sgB;
                gates_phase(GA, GB, t);
            }
        } else {
            // ---- stage emb(t+3) into ring buf (t+3)&3 ----
            if (t + 3 < T_) {
                int tok = s_idx[(t + 3) * 16 + m16];
                if (TAB) {
                    gld16(embb + (size_t)tok * E_ + skoff,
                          &s_ef[(t + 3) & 3][(wave - 8) * 512]);
                } else {
                    const float* pr = embf + (size_t)tok * E_ + skoff;
                    float4 f0 = *(const float4*)pr;
                    float4 f1 = *(const float4*)(pr + 4);
                    u32x4 w;
                    w[0] = cvt_pk_bf16(f0.x, f0.y);
                    w[1] = cvt_pk_bf16(f0.z, f0.w);
                    w[2] = cvt_pk_bf16(f1.x, f1.y);
                    w[3] = cvt_pk_bf16(f1.z, f1.w);
                    *(u32x4*)(&s_ef[(t + 3) & 3][0] + sbase) = w;
                }
            }
        }
        if (TAB) {
            asm volatile("s_waitcnt vmcnt(1) lgkmcnt(0)" ::: "memory");
            __builtin_amdgcn_s_barrier();
            __builtin_amdgcn_sched_barrier(0);
        } else {
            __syncthreads();
        }
    }

    if (wave < 8) {
        const int j = wave * 8 + u;
        out[(r0 + m0) * H_ + j]     = h0v;
        out[(r0 + m0 + 1) * H_ + j] = h1v;
    }
}

// ---------------------------------------------------------------------------
extern "C" void kernel_launch(void* const* d_in, const int* in_sizes, int n_in,
                              void* d_out, int out_size, void* d_ws, size_t ws_size,
                              hipStream_t stream) {
    const int*   x         = (const int*)d_in[0];
    const float* emb_table = (const float*)d_in[1];
    const float* W_ih      = (const float*)d_in[2];
    const float* W_hh      = (const float*)d_in[3];
    const float* b_ih      = (const float*)d_in[4];
    const float* b_hh      = (const float*)d_in[5];
    float*       out       = (float*)d_out;

    short* wih_frag = (short*)d_ws;               // 65536 shorts (128 KB)
    short* whh_g    = wih_frag + 65536;           // 16384 shorts (32 KB)
    float* bias_f   = (float*)(whh_g + 16384);    // 256 floats (1 KB)
    short* emb_bf   = (short*)(bias_f + 256);     // 8.192M shorts (16.4 MB)

    const size_t need = (size_t)(65536 + 16384) * 2 + 256 * 4
                      + (size_t)V_ * E_ * 2;
    const int tab = (ws_size >= need) ? 1 : 0;

    prep_kernel<<<tab ? 2048 : 64, 256, 0, stream>>>(
        W_ih, W_hh, b_ih, b_hh, emb_table,
        wih_frag, whh_g, bias_f,
        tab ? emb_bf : wih_frag, tab ? V_ * E_ : 0);

    if (tab) {
        lstm_f<1><<<B_ / 16, THREADS, 0, stream>>>(
            x, emb_table, emb_bf, wih_frag, whh_g, bias_f, out);
    } else {
        lstm_f<0><<<B_ / 16, THREADS, 0, stream>>>(
            x, emb_table, wih_frag, wih_frag, whh_g, bias_f, out);
    }
}

// Round 16
// 63.272 us; speedup vs baseline: 1.0707x; 1.0483x over previous
//
#include <hip/hip_runtime.h>
#include <math.h>

#define B_ 4096
#define T_ 64
#define E_ 256
#define H_ 64
#define V_ 32000
#define THREADS 768

typedef __attribute__((ext_vector_type(8))) short bf16x8;
typedef __attribute__((ext_vector_type(4))) float f32x4;
typedef __attribute__((ext_vector_type(4))) unsigned int u32x4;

__device__ __forceinline__ short f2bf(float x) {
    unsigned u = __float_as_uint(x);
    return (short)((u + 0x7FFFu + ((u >> 16) & 1u)) >> 16);
}
__device__ __forceinline__ unsigned cvt_pk_bf16(float lo, float hi) {
    unsigned r;
    asm("v_cvt_pk_bf16_f32 %0, %1, %2" : "=v"(r) : "v"(lo), "v"(hi));
    return r;
}
__device__ __forceinline__ float exp2_raw(float x) {
    float r; asm("v_exp_f32 %0, %1" : "=v"(r) : "v"(x)); return r;
}
__device__ __forceinline__ float rcp_raw(float x) {
    float r; asm("v_rcp_f32 %0, %1" : "=v"(r) : "v"(x)); return r;
}
#define LOG2E 1.442695041f

// quad_perm DPP lane exchange (VALU, not DS): xor1 = 0xB1, xor2 = 0x4E.
template <int CTRL>
__device__ __forceinline__ float dpp_f(float x) {
    return __int_as_float(
        __builtin_amdgcn_mov_dpp(__float_as_int(x), CTRL, 0xF, 0xF, true));
}

__device__ __forceinline__ void gld16(const void* g, void* l) {
    __builtin_amdgcn_global_load_lds(
        (const __attribute__((address_space(1))) void*)g,
        (__attribute__((address_space(3))) void*)l, 16, 0, 0);
}

// ---------------------------------------------------------------------------
// Prep (wih_frag layout identical to R4-R15, verified):
//  wih_frag[((vv*2+tl)*8 + kc)*512 + lane*8 + jj]:
//    gate g = tl*128 + (lane&1)*64 + vv*8 + ((lane&15)>>1)
//    k      = kc*32 + (lane>>4)*8 + jj
//  whh_g: bf16 [g][k] row-major;  bias_f = b_ih + b_hh
//  emb_bf: whole table bf16 (RNE); uint4-wide conversion.
// ---------------------------------------------------------------------------
__global__ void prep_kernel(const float* __restrict__ W_ih,
                            const float* __restrict__ W_hh,
                            const float* __restrict__ b_ih,
                            const float* __restrict__ b_hh,
                            const float* __restrict__ emb_table,
                            short* __restrict__ wih_frag,
                            short* __restrict__ whh_g,
                            float* __restrict__ bias_f,
                            short* __restrict__ emb_bf,
                            int tabN) {
    int tid = blockIdx.x * blockDim.x + threadIdx.x;
    int stride = gridDim.x * blockDim.x;
    for (int i = tid; i < 65536; i += stride) {
        int jj = i & 7;
        int l  = (i >> 3) & 63;
        int kc = (i >> 9) & 7;
        int tl = (i >> 12) & 1;
        int vv = i >> 13;
        int uu = (l & 15) >> 1, pp = l & 1;
        int g = tl * 128 + pp * 64 + vv * 8 + uu;
        int k = kc * 32 + (l >> 4) * 8 + jj;
        wih_frag[i] = f2bf(W_ih[g * E_ + k]);
    }
    for (int i = tid; i < 256 * 64; i += stride) whh_g[i] = f2bf(W_hh[i]);
    for (int i = tid; i < 256; i += stride) bias_f[i] = b_ih[i] + b_hh[i];
    for (int i = tid; i < (tabN >> 3); i += stride) {
        float4 v0 = ((const float4*)emb_table)[i * 2];
        float4 v1 = ((const float4*)emb_table)[i * 2 + 1];
        u32x4 w;
        w[0] = cvt_pk_bf16(v0.x, v0.y);
        w[1] = cvt_pk_bf16(v0.z, v0.w);
        w[2] = cvt_pk_bf16(v1.x, v1.y);
        w[3] = cvt_pk_bf16(v1.z, v1.w);
        ((u32x4*)emb_bf)[i] = w;
    }
}

// ---------------------------------------------------------------------------
// 3-waves/EU MFMA LSTM: 768 threads = 12 waves (2 compute + 1 stage / SIMD),
// pinned waves_per_eu(3,3) -> 170-VGPR budget. grid 256 (1 block/CU).
//  waves 0-7 (compute): wave w owns vv=w. W_ih + W_hh register-resident.
//    SPLIT-K: 4 independent MFMA chains (a0/a1 = i|f over kc0-3/kc4-7 + hv0/
//    hv1; b0/b1 same for g|o) -> dep depth 5 not 10; merged to ga/gb in REGS
//    (no LDS stash -- 170-reg budget holds ga/gb live through P, the thing
//    that spilled at 128 in R11).
//    Anti-phase: waves 0-3 gates-then-P; waves 4-7 P-then-gates (each SIMD's
//    two compute waves run MFMA-heavy and trans-heavy phases interleaved).
//  waves 8-11 (stage): wave 8+s stages chunks kc=2s,2s+1 of emb(t+3) via TWO
//    global_load_lds dwordx4 (bf16 table), distance-3 prefetch, 4-ring.
//    Barrier: s_waitcnt vmcnt(2) -- the fresh pair stays in flight, the
//    2-step-old pair is retired before its buffer is read.
// Gates: raw v_exp/v_rcp + quad_perm DPP (VALU-only).
// Fragment LDS layout (zero-conflict): chunk (kc,lane) at kc*1024B + lane*16B.
// ---------------------------------------------------------------------------
template <int TAB>
__global__ __attribute__((amdgpu_flat_work_group_size(THREADS, THREADS),
                          amdgpu_waves_per_eu(3, 3)))
void lstm_f(const int* __restrict__ x,
            const float* __restrict__ embf,
            const short* __restrict__ embb,
            const short* __restrict__ wih_frag,
            const short* __restrict__ whh_g,
            const float* __restrict__ bias_f,
            float* __restrict__ out) {
    __shared__ __align__(16) short s_ef[4][4096];   // 4-ring emb, 8 KB each
    __shared__ __align__(16) short s_hf[2][1024];   // 2-ring h, 2 KB each
    __shared__ int s_idx[1024];                     // [t][m]

    const int tid  = threadIdx.x;
    const int lane = tid & 63;
    const int wave = tid >> 6;
    const int r0   = blockIdx.x * 16;

    for (int i = tid; i < 1024; i += THREADS)
        s_idx[(i & 63) * 16 + (i >> 6)] = x[(r0 + (i >> 6)) * T_ + (i & 63)];
    for (int i = tid; i < 1024; i += THREADS)
        ((int*)s_hf)[i] = 0;

    const int p  = lane & 1;
    const int c4 = lane >> 4;
    const int u  = (lane & 15) >> 1;
    const float scl2 = p ? 1.0f : 2.0f;
    const float offB = p ? 0.0f : -1.0f;
    const float enB  = -LOG2E * scl2;
    const int m0 = c4 * 4 + p * 2;

    // ---- compute-wave setup ----
    bf16x8 wA[8], wB[8], qA0, qA1, qB0, qB1;
    float bA = 0.f, bB = 0.f;
    int hw_s = 0;
    if (wave < 8) {
        const short* wp = wih_frag + wave * 8192 + lane * 8;
        #pragma unroll
        for (int kc = 0; kc < 8; ++kc) {
            wA[kc] = *(const bf16x8*)(wp + kc * 512);
            wB[kc] = *(const bf16x8*)(wp + 4096 + kc * 512);
        }
        const int gA = p * 64 + wave * 8 + u;
        const short* qp = whh_g + gA * 64 + c4 * 8;
        qA0 = *(const bf16x8*)(qp);
        qA1 = *(const bf16x8*)(qp + 32);
        qB0 = *(const bf16x8*)(qp + 8192);
        qB1 = *(const bf16x8*)(qp + 8192 + 32);
        bA = bias_f[gA];
        bB = bias_f[gA + 128];
        hw_s = (wave >> 2) * 512 + (wave & 3) * 128
             + ((u & 1) ? (m0 + 1) * 8 + (u - 1) : m0 * 8 + u);
    }

    // ---- stage-wave mapping: wave 8+s owns chunks kc=2s, 2s+1 ----
    const int m16    = lane & 15;
    const int kc0    = (wave - 8) * 2;
    const int sbase0 = kc0 * 512 + lane * 8;                    // shorts
    const int skoff0 = kc0 * 32 + (lane >> 4) * 8;              // emb col
    const int skoff1 = skoff0 + 32;

    __syncthreads();   // s_idx, h=0 visible

    if (wave >= 8) {
        // prologue: stage t=0,1,2 (t0,t1 must land; t2 pair may stay in flight)
        #pragma unroll
        for (int tt = 0; tt < 3; ++tt) {
            int tok = s_idx[tt * 16 + m16];
            if (TAB) {
                gld16(embb + (size_t)tok * E_ + skoff0, &s_ef[tt][kc0 * 512]);
                gld16(embb + (size_t)tok * E_ + skoff1, &s_ef[tt][kc0 * 512 + 512]);
            } else {
                const float* pr = embf + (size_t)tok * E_;
                #pragma unroll
                for (int kk = 0; kk < 2; ++kk) {
                    const float* q = pr + skoff0 + kk * 32;
                    float4 f0 = *(const float4*)q;
                    float4 f1 = *(const float4*)(q + 4);
                    u32x4 w;
                    w[0] = cvt_pk_bf16(f0.x, f0.y);
                    w[1] = cvt_pk_bf16(f0.z, f0.w);
                    w[2] = cvt_pk_bf16(f1.x, f1.y);
                    w[3] = cvt_pk_bf16(f1.z, f1.w);
                    *(u32x4*)(&s_ef[tt][0] + sbase0 + kk * 512) = w;
                }
            }
        }
    }
    if (TAB) {
        asm volatile("s_waitcnt vmcnt(2) lgkmcnt(0)" ::: "memory");
        __builtin_amdgcn_s_barrier();
        __builtin_amdgcn_sched_barrier(0);
    } else {
        __syncthreads();
    }

    float c0 = 0.f, c1 = 0.f, h0v = 0.f, h1v = 0.f;
    f32x4 a0, a1, b0, b1;   // split-K accumulator chains

    // ---- compute prologue: pre-gates P(0) from buf0 (split-K) ----
    if (wave < 8) {
        a0 = (f32x4){bA, bA, bA, bA};
        b0 = (f32x4){bB, bB, bB, bB};
        a1 = (f32x4){0.f, 0.f, 0.f, 0.f};
        b1 = (f32x4){0.f, 0.f, 0.f, 0.f};
        const short* eb = &s_ef[0][0] + lane * 8;
        #pragma unroll
        for (int kc = 0; kc < 4; ++kc) {
            bf16x8 av = *(const bf16x8*)(eb + kc * 512);
            bf16x8 aw = *(const bf16x8*)(eb + (kc + 4) * 512);
            a0 = __builtin_amdgcn_mfma_f32_16x16x32_bf16(av, wA[kc], a0, 0, 0, 0);
            b0 = __builtin_amdgcn_mfma_f32_16x16x32_bf16(av, wB[kc], b0, 0, 0, 0);
            a1 = __builtin_amdgcn_mfma_f32_16x16x32_bf16(aw, wA[kc + 4], a1, 0, 0, 0);
            b1 = __builtin_amdgcn_mfma_f32_16x16x32_bf16(aw, wB[kc + 4], b1, 0, 0, 0);
        }
    }

    // gates: full gate math from merged pre-activations, h-write for step t
    auto gates_phase = [&](const float* ga, const float* gb, int t) {
        float sA[4], Bv[4];
        #pragma unroll
        for (int q = 0; q < 4; ++q) {
            sA[q] = rcp_raw(1.0f + exp2_raw(-LOG2E * ga[q]));           // sigm(i)|sigm(f)
            Bv[q] = rcp_raw(1.0f + exp2_raw(enB * gb[q])) * scl2 + offB; // tanh(g)|sigm(o)
        }
        float s1 = p ? sA[0] : sA[2] * Bv[2];
        float r1 = dpp_f<0xB1>(s1);
        float s2 = p ? sA[1] : sA[3] * Bv[3];
        float r2 = dpp_f<0xB1>(s2);
        float r3 = dpp_f<0xB1>(Bv[0]);
        float r4 = dpp_f<0xB1>(Bv[1]);
        float fc0 = p ? sA[2] : r1;
        float ic0 = p ? r1 : sA[0] * Bv[0];
        float oc0 = p ? Bv[2] : r3;
        float fc1 = p ? sA[3] : r2;
        float ic1 = p ? r2 : sA[1] * Bv[1];
        float oc1 = p ? Bv[3] : r4;
        c0 = fc0 * c0 + ic0;
        c1 = fc1 * c1 + ic1;
        h0v = oc0 * (1.0f - 2.0f * rcp_raw(1.0f + exp2_raw(2.0f * LOG2E * c0)));
        h1v = oc1 * (1.0f - 2.0f * rcp_raw(1.0f + exp2_raw(2.0f * LOG2E * c1)));
        float snd = (u & 1) ? h0v : h1v;
        float rcv = dpp_f<0x4E>(snd);
        unsigned hw = (u & 1) ? cvt_pk_bf16(rcv, h1v) : cvt_pk_bf16(h0v, rcv);
        *(unsigned*)(&s_hf[(t + 1) & 1][0] + hw_s) = hw;
    };

    auto p_phase = [&](int t) {   // preG(t+1), split-K chains
        a0 = (f32x4){bA, bA, bA, bA};
        b0 = (f32x4){bB, bB, bB, bB};
        a1 = (f32x4){0.f, 0.f, 0.f, 0.f};
        b1 = (f32x4){0.f, 0.f, 0.f, 0.f};
        const short* eb = &s_ef[(t + 1) & 3][0] + lane * 8;
        __builtin_amdgcn_s_setprio(1);
        #pragma unroll
        for (int kc = 0; kc < 4; ++kc) {
            bf16x8 av = *(const bf16x8*)(eb + kc * 512);
            bf16x8 aw = *(const bf16x8*)(eb + (kc + 4) * 512);
            a0 = __builtin_amdgcn_mfma_f32_16x16x32_bf16(av, wA[kc], a0, 0, 0, 0);
            b0 = __builtin_amdgcn_mfma_f32_16x16x32_bf16(av, wB[kc], b0, 0, 0, 0);
            a1 = __builtin_amdgcn_mfma_f32_16x16x32_bf16(aw, wA[kc + 4], a1, 0, 0, 0);
            b1 = __builtin_amdgcn_mfma_f32_16x16x32_bf16(aw, wB[kc + 4], b1, 0, 0, 0);
        }
        __builtin_amdgcn_s_setprio(0);
    };

    #pragma unroll 4
    for (int t = 0; t < T_; ++t) {
        if (wave < 8) {
            // ---- R: G(t) = preG + h(t-1)*Whh (4 independent chains) ----
            const short* hb = &s_hf[t & 1][0] + lane * 8;
            bf16x8 hv0 = *(const bf16x8*)(hb);
            bf16x8 hv1 = *(const bf16x8*)(hb + 512);
            __builtin_amdgcn_s_setprio(1);
            a0 = __builtin_amdgcn_mfma_f32_16x16x32_bf16(hv0, qA0, a0, 0, 0, 0);
            a1 = __builtin_amdgcn_mfma_f32_16x16x32_bf16(hv1, qA1, a1, 0, 0, 0);
            b0 = __builtin_amdgcn_mfma_f32_16x16x32_bf16(hv0, qB0, b0, 0, 0, 0);
            b1 = __builtin_amdgcn_mfma_f32_16x16x32_bf16(hv1, qB1, b1, 0, 0, 0);
            __builtin_amdgcn_s_setprio(0);

            // ---- merge split-K into registers ----
            float ga[4], gb[4];
            #pragma unroll
            for (int q = 0; q < 4; ++q) {
                ga[q] = a0[q] + a1[q];
                gb[q] = b0[q] + b1[q];
            }

            if (wave < 4) {
                // ---- group A: gates first, then P ----
                gates_phase(ga, gb, t);
                if (t < T_ - 1) p_phase(t);
            } else {
                // ---- group B: P first (ga/gb live in regs), then gates ----
                __builtin_amdgcn_sched_barrier(0);
                if (t < T_ - 1) p_phase(t);
                __builtin_amdgcn_sched_barrier(0);
                gates_phase(ga, gb, t);
            }
        } else {
            // ---- stage emb(t+3) chunks kc0,kc0+1 into ring buf (t+3)&3 ----
            if (t + 3 < T_) {
                int tok = s_idx[(t + 3) * 16 + m16];
                if (TAB) {
                    gld16(embb + (size_t)tok * E_ + skoff0,
                          &s_ef[(t + 3) & 3][kc0 * 512]);
                    gld16(embb + (size_t)tok * E_ + skoff1,
                          &s_ef[(t + 3) & 3][kc0 * 512 + 512]);
                } else {
                    const float* pr = embf + (size_t)tok * E_;
                    #pragma unroll
                    for (int kk = 0; kk < 2; ++kk) {
                        const float* q = pr + skoff0 + kk * 32;
                        float4 f0 = *(const float4*)q;
                        float4 f1 = *(const float4*)(q + 4);
                        u32x4 w;
                        w[0] = cvt_pk_bf16(f0.x, f0.y);
                        w[1] = cvt_pk_bf16(f0.z, f0.w);
                        w[2] = cvt_pk_bf16(f1.x, f1.y);
                        w[3] = cvt_pk_bf16(f1.z, f1.w);
                        *(u32x4*)(&s_ef[(t + 3) & 3][0] + sbase0 + kk * 512) = w;
                    }
                }
            }
        }
        if (TAB) {
            // fresh pair stays in flight; the 2-step-old pair must retire
            asm volatile("s_waitcnt vmcnt(2) lgkmcnt(0)" ::: "memory");
            __builtin_amdgcn_s_barrier();
            __builtin_amdgcn_sched_barrier(0);
        } else {
            __syncthreads();
        }
    }

    if (wave < 8) {
        const int j = wave * 8 + u;
        out[(r0 + m0) * H_ + j]     = h0v;
        out[(r0 + m0 + 1) * H_ + j] = h1v;
    }
}

// ---------------------------------------------------------------------------
extern "C" void kernel_launch(void* const* d_in, const int* in_sizes, int n_in,
                              void* d_out, int out_size, void* d_ws, size_t ws_size,
                              hipStream_t stream) {
    const int*   x         = (const int*)d_in[0];
    const float* emb_table = (const float*)d_in[1];
    const float* W_ih      = (const float*)d_in[2];
    const float* W_hh      = (const float*)d_in[3];
    const float* b_ih      = (const float*)d_in[4];
    const float* b_hh      = (const float*)d_in[5];
    float*       out       = (float*)d_out;

    short* wih_frag = (short*)d_ws;               // 65536 shorts (128 KB)
    short* whh_g    = wih_frag + 65536;           // 16384 shorts (32 KB)
    float* bias_f   = (float*)(whh_g + 16384);    // 256 floats (1 KB)
    short* emb_bf   = (short*)(bias_f + 256);     // 8.192M shorts (16.4 MB)

    const size_t need = (size_t)(65536 + 16384) * 2 + 256 * 4
                      + (size_t)V_ * E_ * 2;
    const int tab = (ws_size >= need) ? 1 : 0;

    prep_kernel<<<tab ? 2048 : 64, 256, 0, stream>>>(
        W_ih, W_hh, b_ih, b_hh, emb_table,
        wih_frag, whh_g, bias_f,
        tab ? emb_bf : wih_frag, tab ? V_ * E_ : 0);

    if (tab) {
        lstm_f<1><<<B_ / 16, THREADS, 0, stream>>>(
            x, emb_table, emb_bf, wih_frag, whh_g, bias_f, out);
    } else {
        lstm_f<0><<<B_ / 16, THREADS, 0, stream>>>(
            x, emb_table, wih_frag, wih_frag, whh_g, bias_f, out);
    }
}